// Round 5
// baseline (379.845 us; speedup 1.0000x reference)
//
#include <hip/hip_runtime.h>
#include <math.h>

// (T,B,C,H,W) = (9,8,256,56,56), fp32.
// One pass over seq with ONLINE softmax over t (state in registers):
//   per (t): coalesced 128B-line loads -> score partial -> shfl butterfly
//   -> 4-wave LDS exchange (1 barrier/t) -> online update of (m,s,acc).
// Math note (validated rounds 1-4, absmax 7.8e-3): score_center and bias
// are constant along softmax axis t -> shift-invariant -> dropped.
#define TT 9
#define BN 8
#define CC 256
#define HW 3136
#define WIN 98        // 32-pixel windows per image (3136/32)
#define CENTER_T 4

#define F4OP(d, expr_x, expr_y, expr_z, expr_w) \
  d.x = expr_x; d.y = expr_y; d.z = expr_z; d.w = expr_w;

__global__ __launch_bounds__(256, 2) void online_fused_kernel(
    const float* __restrict__ seq, const float* __restrict__ w,
    const float* __restrict__ gamma, float* __restrict__ out) {
  int blk = blockIdx.x;
  int b = blk / WIN;
  int win = blk - b * WIN;
  int px0 = win * 32;
  int tid = threadIdx.x;
  int wv = tid >> 6;
  int l = tid & 63;
  int quad = l & 7;     // pixel quad: px = px0 + quad*4 .. +3
  int chg = l >> 3;     // channel-group within wave (0..7)
  int slot = wv * 8 + chg;  // 0..31
  int c0 = slot * 8;        // this thread's 8 consecutive channels
  int px = px0 + quad * 4;

  __shared__ float4 red[TT][4][8];  // [t][wave][quad] partial scores

  // weights for this thread's channels (broadcast loads, L1-served)
  float4 wa = *(const float4*)(w + CC + c0);
  float4 wb = *(const float4*)(w + CC + c0 + 4);
  float wk[8] = {wa.x, wa.y, wa.z, wa.w, wb.x, wb.y, wb.z, wb.w};

  float4 m4 = {-1e30f, -1e30f, -1e30f, -1e30f};
  float4 s4 = {0.f, 0.f, 0.f, 0.f};
  float4 acc[8], cen[8];
  #pragma unroll
  for (int k = 0; k < 8; ++k) acc[k] = {0.f, 0.f, 0.f, 0.f};
  #pragma unroll
  for (int k = 0; k < 8; ++k) cen[k] = {0.f, 0.f, 0.f, 0.f};

  #pragma unroll
  for (int t = 0; t < TT; ++t) {
    // ---- load this t's 8 channels x 4 px (one 128B line per row/wave) ----
    const float* bp = seq + (((size_t)t * BN + b) * CC + c0) * HW + px;
    float4 v[8];
    #pragma unroll
    for (int k = 0; k < 8; ++k) v[k] = *(const float4*)(bp + (size_t)k * HW);

    // ---- partial score over 8 channels, per pixel ----
    float4 p = {0.f, 0.f, 0.f, 0.f};
    #pragma unroll
    for (int k = 0; k < 8; ++k) {
      p.x = fmaf(wk[k], v[k].x, p.x);
      p.y = fmaf(wk[k], v[k].y, p.y);
      p.z = fmaf(wk[k], v[k].z, p.z);
      p.w = fmaf(wk[k], v[k].w, p.w);
    }
    // ---- butterfly over the 8 channel-groups (lanes q, q+8, ..., q+56) ----
    #pragma unroll
    for (int mask = 8; mask <= 32; mask <<= 1) {
      p.x += __shfl_xor(p.x, mask, 64);
      p.y += __shfl_xor(p.y, mask, 64);
      p.z += __shfl_xor(p.z, mask, 64);
      p.w += __shfl_xor(p.w, mask, 64);
    }
    // ---- cross-wave exchange (channels split over 4 waves) ----
    if (chg == 0) red[t][wv][quad] = p;
    __syncthreads();
    float4 r0 = red[t][0][quad], r1 = red[t][1][quad];
    float4 r2 = red[t][2][quad], r3 = red[t][3][quad];
    float4 sc;
    F4OP(sc, r0.x + r1.x + r2.x + r3.x, r0.y + r1.y + r2.y + r3.y,
             r0.z + r1.z + r2.z + r3.z, r0.w + r1.w + r2.w + r3.w)

    // ---- online softmax update ----
    float4 mn;
    F4OP(mn, fmaxf(m4.x, sc.x), fmaxf(m4.y, sc.y),
             fmaxf(m4.z, sc.z), fmaxf(m4.w, sc.w))
    float4 al;
    F4OP(al, __expf(m4.x - mn.x), __expf(m4.y - mn.y),
             __expf(m4.z - mn.z), __expf(m4.w - mn.w))
    float4 e;
    F4OP(e, __expf(sc.x - mn.x), __expf(sc.y - mn.y),
            __expf(sc.z - mn.z), __expf(sc.w - mn.w))
    F4OP(s4, fmaf(s4.x, al.x, e.x), fmaf(s4.y, al.y, e.y),
             fmaf(s4.z, al.z, e.z), fmaf(s4.w, al.w, e.w))
    m4 = mn;
    #pragma unroll
    for (int k = 0; k < 8; ++k) {
      acc[k].x = fmaf(acc[k].x, al.x, e.x * v[k].x);
      acc[k].y = fmaf(acc[k].y, al.y, e.y * v[k].y);
      acc[k].z = fmaf(acc[k].z, al.z, e.z * v[k].z);
      acc[k].w = fmaf(acc[k].w, al.w, e.w * v[k].w);
    }
    if (t == CENTER_T) {
      #pragma unroll
      for (int k = 0; k < 8; ++k) cen[k] = v[k];
    }
  }

  // ---- epilogue: out = center + gamma * acc / s ----
  float gm = gamma[0];
  float4 gi;
  F4OP(gi, gm / s4.x, gm / s4.y, gm / s4.z, gm / s4.w)
  float* ob = out + ((size_t)b * CC + c0) * HW + px;
  #pragma unroll
  for (int k = 0; k < 8; ++k) {
    float4 o;
    o.x = fmaf(gi.x, acc[k].x, cen[k].x);
    o.y = fmaf(gi.y, acc[k].y, cen[k].y);
    o.z = fmaf(gi.z, acc[k].z, cen[k].z);
    o.w = fmaf(gi.w, acc[k].w, cen[k].w);
    *(float4*)(ob + (size_t)k * HW) = o;
  }
}

extern "C" void kernel_launch(void* const* d_in, const int* in_sizes, int n_in,
                              void* d_out, int out_size, void* d_ws, size_t ws_size,
                              hipStream_t stream) {
  const float* seq = (const float*)d_in[0];
  const float* w = (const float*)d_in[1];
  // d_in[2] (bias) unused: softmax shift-invariant.
  const float* gamma = (const float*)d_in[3];
  float* out = (float*)d_out;

  online_fused_kernel<<<BN * WIN, 256, 0, stream>>>(seq, w, gamma, out);
}

// Round 6
// 357.893 us; speedup vs baseline: 1.0613x; 1.0613x over previous
//
#include <hip/hip_runtime.h>
#include <math.h>

// (T,B,C,H,W) = (9,8,256,56,56), fp32.
// Two-phase single kernel, ONE barrier:
//   Pass 1: stream seq (full-128B-line coalescing: wave spans 32 px per
//           channel row), score partials -> shfl butterfly -> LDS slots.
//   Softmax over t in registers; center + gamma + 1/s folded into coef[t]:
//           out = sum_t (g*e_t/s + [t==4]) * v_t   (no cen array, no div)
//   Pass 2: re-read seq (block's own 288 KB -> L2/L3-hot), accumulate, store.
// Math note (validated rounds 1-5, absmax 7.8e-3): score_center and bias
// are constant along softmax axis t -> shift-invariant -> dropped.
#define TT 9
#define BN 8
#define CC 256
#define HW 3136
#define WIN 98        // 32-pixel windows per image
#define CENTER_T 4

__global__ __launch_bounds__(256) void two_phase_kernel(
    const float* __restrict__ seq, const float* __restrict__ w,
    const float* __restrict__ gamma, float* __restrict__ out) {
  int blk = blockIdx.x;
  int b = blk / WIN;
  int win = blk - b * WIN;
  int px0 = win * 32;
  int tid = threadIdx.x;
  int wv = tid >> 6;
  int l = tid & 63;
  int quad = l & 7;          // pixel quad: px = px0 + quad*4
  int chg = l >> 3;          // channel-group within wave
  int c0 = (wv * 8 + chg) * 8;  // 8 consecutive channels
  int px = px0 + quad * 4;

  __shared__ float4 red[TT][4][8];  // [t][wave][quad], write-once slots

  float4 wa = *(const float4*)(w + CC + c0);
  float4 wb = *(const float4*)(w + CC + c0 + 4);
  float wk[8] = {wa.x, wa.y, wa.z, wa.w, wb.x, wb.y, wb.z, wb.w};

  const size_t tstride = (size_t)BN * CC * HW;
  const float* bp0 = seq + ((size_t)b * CC + c0) * HW + px;

  // ---- Pass 1: scores only (v transient), no intra-loop barrier ----
  #pragma unroll
  for (int t = 0; t < TT; ++t) {
    const float* bp = bp0 + t * tstride;
    float4 p = {0.f, 0.f, 0.f, 0.f};
    #pragma unroll
    for (int k = 0; k < 8; ++k) {
      float4 v = *(const float4*)(bp + (size_t)k * HW);
      p.x = fmaf(wk[k], v.x, p.x);
      p.y = fmaf(wk[k], v.y, p.y);
      p.z = fmaf(wk[k], v.z, p.z);
      p.w = fmaf(wk[k], v.w, p.w);
    }
    #pragma unroll
    for (int mask = 8; mask <= 32; mask <<= 1) {
      p.x += __shfl_xor(p.x, mask, 64);
      p.y += __shfl_xor(p.y, mask, 64);
      p.z += __shfl_xor(p.z, mask, 64);
      p.w += __shfl_xor(p.w, mask, 64);
    }
    if (chg == 0) red[t][wv][quad] = p;
  }
  __syncthreads();  // the only barrier

  // ---- Softmax over t + fold gamma, 1/s, center residual into coef ----
  float4 ct[TT];
  float4 m4 = {-1e30f, -1e30f, -1e30f, -1e30f};
  #pragma unroll
  for (int t = 0; t < TT; ++t) {
    float4 r0 = red[t][0][quad], r1 = red[t][1][quad];
    float4 r2 = red[t][2][quad], r3 = red[t][3][quad];
    float4 s;
    s.x = r0.x + r1.x + r2.x + r3.x;
    s.y = r0.y + r1.y + r2.y + r3.y;
    s.z = r0.z + r1.z + r2.z + r3.z;
    s.w = r0.w + r1.w + r2.w + r3.w;
    ct[t] = s;
    m4.x = fmaxf(m4.x, s.x);
    m4.y = fmaxf(m4.y, s.y);
    m4.z = fmaxf(m4.z, s.z);
    m4.w = fmaxf(m4.w, s.w);
  }
  float4 s4 = {0.f, 0.f, 0.f, 0.f};
  #pragma unroll
  for (int t = 0; t < TT; ++t) {
    ct[t].x = __expf(ct[t].x - m4.x); s4.x += ct[t].x;
    ct[t].y = __expf(ct[t].y - m4.y); s4.y += ct[t].y;
    ct[t].z = __expf(ct[t].z - m4.z); s4.z += ct[t].z;
    ct[t].w = __expf(ct[t].w - m4.w); s4.w += ct[t].w;
  }
  float gm = gamma[0];
  float4 gi = {gm / s4.x, gm / s4.y, gm / s4.z, gm / s4.w};
  #pragma unroll
  for (int t = 0; t < TT; ++t) {
    float add = (t == CENTER_T) ? 1.f : 0.f;
    ct[t].x = fmaf(gi.x, ct[t].x, add);
    ct[t].y = fmaf(gi.y, ct[t].y, add);
    ct[t].z = fmaf(gi.z, ct[t].z, add);
    ct[t].w = fmaf(gi.w, ct[t].w, add);
  }

  // ---- Pass 2: re-read (cache-hot) and accumulate; no barriers ----
  float4 acc[8];
  #pragma unroll
  for (int k = 0; k < 8; ++k) acc[k] = {0.f, 0.f, 0.f, 0.f};
  #pragma unroll
  for (int t = 0; t < TT; ++t) {
    const float* bp = bp0 + t * tstride;
    float4 a = ct[t];
    #pragma unroll
    for (int k = 0; k < 8; ++k) {
      float4 v = *(const float4*)(bp + (size_t)k * HW);
      acc[k].x = fmaf(a.x, v.x, acc[k].x);
      acc[k].y = fmaf(a.y, v.y, acc[k].y);
      acc[k].z = fmaf(a.z, v.z, acc[k].z);
      acc[k].w = fmaf(a.w, v.w, acc[k].w);
    }
  }
  float* ob = out + ((size_t)b * CC + c0) * HW + px;
  #pragma unroll
  for (int k = 0; k < 8; ++k)
    *(float4*)(ob + (size_t)k * HW) = acc[k];
}

extern "C" void kernel_launch(void* const* d_in, const int* in_sizes, int n_in,
                              void* d_out, int out_size, void* d_ws, size_t ws_size,
                              hipStream_t stream) {
  const float* seq = (const float*)d_in[0];
  const float* w = (const float*)d_in[1];
  // d_in[2] (bias) unused: softmax shift-invariant.
  const float* gamma = (const float*)d_in[3];
  float* out = (float*)d_out;

  two_phase_kernel<<<BN * WIN, 256, 0, stream>>>(seq, w, gamma, out);
}